// Round 1
// 422.400 us; speedup vs baseline: 1.0139x; 1.0139x over previous
//
#include <hip/hip_runtime.h>
#include <hip/hip_bf16.h>

#define NT   8
#define INF  128
#define OUTF 64
#define MT   4      // row-tiles per wave-pass (masked fallback)
#define MB   2      // row-tiles per wave-pass (binned main)

typedef __attribute__((ext_vector_type(8))) short short8;   // 8 bf16 (4 VGPRs)
typedef __attribute__((ext_vector_type(4))) float f32x4;

__device__ __forceinline__ short f2bf(float f) {
  __hip_bfloat16 h = __float2bfloat16(f);
  return __builtin_bit_cast(short, h);
}

// ---------------------------------------------------------------------------
// wbf[128 * 512] shorts (128 KB) in d_ws: W as bf16 in MFMA B-fragment order.
//   group g = (t*4 + s), frag fi = g*4 + nb, lane(q,c), j:
//   wbf[fi*512 + lane*8 + j] = bf16( W[t][s*32 + q*8 + j][nb*16 + c] )
// Also zeroes the 8 type-count slots (cnt) for the binning path.
// ---------------------------------------------------------------------------
__global__ void hl_wconv(const float* __restrict__ W, short* __restrict__ wbf,
                         int* __restrict__ cnt) {
  const int tid   = blockIdx.x * blockDim.x + threadIdx.x;  // 0..8191
  const int combo = tid >> 6;                               // 0..127
  const int lane  = tid & 63;
  const int t = combo >> 4, s = (combo >> 2) & 3, nb = combo & 3;
  const int q = lane >> 4, c = lane & 15;
  const float* Wt = W + t * INF * OUTF;
  short8 v;
  #pragma unroll
  for (int j = 0; j < 8; ++j)
    v[j] = f2bf(Wt[(s * 32 + q * 8 + j) * OUTF + nb * 16 + c]);
  *(short8*)(wbf + (size_t)tid * 8) = v;
  if (cnt && tid < NT) cnt[tid] = 0;
}

// ---------------------------------------------------------------------------
// Histogram of node_type into cnt[8] (block-local LDS counts, one global
// atomic per type per block).
// ---------------------------------------------------------------------------
__global__ __launch_bounds__(256) void hl_hist(const int* __restrict__ nty, int N,
                                               int* __restrict__ cnt) {
  __shared__ int h[NT];
  if (threadIdx.x < NT) h[threadIdx.x] = 0;
  __syncthreads();
  const int stride = gridDim.x * 1024;
  for (int i0 = (blockIdx.x * 256 + threadIdx.x) * 4; i0 < N; i0 += stride) {
    if (i0 + 3 < N) {
      int4 v = *(const int4*)(nty + i0);
      atomicAdd(&h[v.x], 1); atomicAdd(&h[v.y], 1);
      atomicAdd(&h[v.z], 1); atomicAdd(&h[v.w], 1);
    } else {
      for (int k = i0; k < N; ++k) atomicAdd(&h[nty[k]], 1);
    }
  }
  __syncthreads();
  if (threadIdx.x < NT && h[threadIdx.x]) atomicAdd(&cnt[threadIdx.x], h[threadIdx.x]);
}

// ---------------------------------------------------------------------------
// Segment offsets: poff[t] = start of type-t segment (padded to 64 rows),
// poff[8] = padded total. cursor[t] = poff[t] (scatter cursors). Pad slots
// [poff[t]+cnt[t], poff[t+1]) get idx = -1.
// ---------------------------------------------------------------------------
__global__ void hl_off(const int* __restrict__ cnt, int* __restrict__ poff,
                       int* __restrict__ cursor, int* __restrict__ idx) {
  __shared__ int sp[NT + 1], sc[NT];
  if (threadIdx.x == 0) {
    int o = 0;
    for (int t = 0; t < NT; ++t) {
      sp[t] = o; sc[t] = cnt[t];
      o += (cnt[t] + 63) & ~63;
      poff[t] = sp[t];
      cursor[t] = sp[t];
    }
    sp[NT] = o;
    poff[NT] = o;
  }
  __syncthreads();
  for (int t = 0; t < NT; ++t)
    for (int k = sp[t] + sc[t] + (int)threadIdx.x; k < sp[t + 1]; k += blockDim.x)
      idx[k] = -1;
}

// ---------------------------------------------------------------------------
// Scatter row indices into type segments. Two-phase per 1024-element chunk:
// LDS count -> one global atomicAdd per type reserves a range -> LDS-ranked
// writes. Order within a type is irrelevant (each row computed independently).
// ---------------------------------------------------------------------------
__global__ __launch_bounds__(256) void hl_scat(const int* __restrict__ nty, int N,
                                               int* __restrict__ cursor,
                                               int* __restrict__ idx) {
  __shared__ int lbase[NT], lcnt[NT];
  const int stride = gridDim.x * 1024;
  for (int cb = blockIdx.x * 1024; cb < N; cb += stride) {
    if (threadIdx.x < NT) lcnt[threadIdx.x] = 0;
    __syncthreads();
    const int i0 = cb + threadIdx.x * 4;
    int t[4]; int nv = 0;
    if (i0 + 3 < N) {
      int4 v = *(const int4*)(nty + i0);
      t[0] = v.x; t[1] = v.y; t[2] = v.z; t[3] = v.w; nv = 4;
    } else {
      for (int k = 0; k < 4 && i0 + k < N; ++k) { t[k] = nty[i0 + k]; ++nv; }
    }
    int lofs[4];
    for (int k = 0; k < nv; ++k) lofs[k] = atomicAdd(&lcnt[t[k]], 1);
    __syncthreads();
    if (threadIdx.x < NT && lcnt[threadIdx.x] > 0)
      lbase[threadIdx.x] = atomicAdd(&cursor[threadIdx.x], lcnt[threadIdx.x]);
    __syncthreads();
    for (int k = 0; k < nv; ++k) idx[lbase[t[k]] + lofs[k]] = i0 + k;
    __syncthreads();
  }
}

// ---------------------------------------------------------------------------
// Binned GEMM: each wave-pass owns 32 padded idx entries (2 tiles of 16), all
// of ONE type (segments 64-aligned). No masking: 1x FLOPs, B = 16 frags/pass.
// Pad entries (idx<0): A-load clamped to row 0, store skipped.
// Fragment mappings identical to the verified masked kernel:
//   A: m = lane&15, k = q*8 + j (per s-step of 32)
//   B: k = s*32 + q*8 + j, n = nb*16 + c
//   C/D: col = lane&15, row = q*4 + reg
// ---------------------------------------------------------------------------
__global__ __launch_bounds__(256, 4) void hl_bgemm(
    const float* __restrict__ x, const short* __restrict__ wbf,
    const float* __restrict__ b, const int* __restrict__ idx,
    const int* __restrict__ poff, float* __restrict__ out) {
  const int wave = threadIdx.x >> 6;
  const int lane = threadIdx.x & 63;
  const int q = lane >> 4, c = lane & 15;
  const short* wp = wbf + (size_t)lane * 8;   // + fi*512 per fragment

  int p[NT + 1];
  #pragma unroll
  for (int t = 0; t <= NT; ++t) p[t] = poff[t];
  const int npass = p[NT] >> 5;               // 32 rows per pass
  const int nwaves = gridDim.x * 4;

  for (int pass = blockIdx.x * 4 + wave; pass < npass; pass += nwaves) {
    const int base = pass * 32;
    int t = 0;
    #pragma unroll
    for (int k = 1; k < NT; ++k) t += (base >= p[k]);

    // ---- A rows (gather) ----
    int rows[MB];
    #pragma unroll
    for (int i = 0; i < MB; ++i) rows[i] = idx[base + i * 16 + c];

    short8 A[MB][4];
    #pragma unroll
    for (int i = 0; i < MB; ++i) {
      const int r = rows[i] < 0 ? 0 : rows[i];
      const float* xr = x + (size_t)r * INF;
      #pragma unroll
      for (int s = 0; s < 4; ++s) {
        f32x4 v0 = *(const f32x4*)(xr + s * 32 + q * 8);
        f32x4 v1 = *(const f32x4*)(xr + s * 32 + q * 8 + 4);
        short8 a;
        #pragma unroll
        for (int j = 0; j < 4; ++j) { a[j] = f2bf(v0[j]); a[j + 4] = f2bf(v1[j]); }
        A[i][s] = a;
      }
    }

    f32x4 acc[MB][4];
    #pragma unroll
    for (int i = 0; i < MB; ++i)
      #pragma unroll
      for (int nb = 0; nb < 4; ++nb) acc[i][nb] = (f32x4){0, 0, 0, 0};

    #pragma unroll
    for (int s = 0; s < 4; ++s) {
      short8 B[4];
      #pragma unroll
      for (int nb = 0; nb < 4; ++nb)
        B[nb] = *(const short8*)(wp + (size_t)(((t * 4 + s) * 4 + nb)) * 512);
      #pragma unroll
      for (int i = 0; i < MB; ++i)
        #pragma unroll
        for (int nb = 0; nb < 4; ++nb)
          acc[i][nb] = __builtin_amdgcn_mfma_f32_16x16x32_bf16(A[i][s], B[nb], acc[i][nb], 0, 0, 0);
    }

    // ---- epilogue: single-type bias, scatter stores, skip pad rows ----
    float bv[4];
    #pragma unroll
    for (int nb = 0; nb < 4; ++nb) bv[nb] = b[t * OUTF + nb * 16 + c];
    #pragma unroll
    for (int i = 0; i < MB; ++i) {
      int4 iv = *(const int4*)(idx + base + i * 16 + q * 4);
      const int rr[4] = {iv.x, iv.y, iv.z, iv.w};
      #pragma unroll
      for (int r = 0; r < 4; ++r) {
        if (rr[r] >= 0) {
          float* orow = out + (size_t)rr[r] * OUTF + c;
          #pragma unroll
          for (int nb = 0; nb < 4; ++nb)
            orow[nb * 16] = acc[i][nb][r] + bv[nb];
        }
      }
    }
  }
}

// ---------------------------------------------------------------------------
// Fallback: previous masked multi-type GEMM (used only if ws too small for
// the index buffer). Verified in earlier rounds.
// ---------------------------------------------------------------------------
__global__ __launch_bounds__(256, 2) void hl_main_masked(
    const float* __restrict__ x, const int* __restrict__ nty,
    const short* __restrict__ wbf, const float* __restrict__ b,
    float* __restrict__ out, int N) {
  const int npass = (N + 63) >> 6;
  const int wave = threadIdx.x >> 6;
  const int lane = threadIdx.x & 63;
  const int q = lane >> 4, c = lane & 15;
  const int nwaves = gridDim.x * 4;
  const short* wp = wbf + (size_t)lane * 8;

  for (int pass = blockIdx.x * 4 + wave; pass < npass; pass += nwaves) {
    const int base = pass * 64;

    short8 A[MT][4];
    int tys[MT];
    #pragma unroll
    for (int i = 0; i < MT; ++i) {
      int rowa = base + i * 16 + c;
      if (rowa > N - 1) rowa = N - 1;
      tys[i] = nty[rowa];
      const float* xr = x + (size_t)rowa * INF;
      #pragma unroll
      for (int s = 0; s < 4; ++s) {
        f32x4 v0 = *(const f32x4*)(xr + s * 32 + q * 8);
        f32x4 v1 = *(const f32x4*)(xr + s * 32 + q * 8 + 4);
        short8 a;
        #pragma unroll
        for (int j = 0; j < 4; ++j) { a[j] = f2bf(v0[j]); a[j + 4] = f2bf(v1[j]); }
        A[i][s] = a;
      }
    }

    f32x4 acc[MT][4];
    #pragma unroll
    for (int i = 0; i < MT; ++i)
      #pragma unroll
      for (int nb = 0; nb < 4; ++nb) acc[i][nb] = (f32x4){0, 0, 0, 0};

    const short8 z8 = {0, 0, 0, 0, 0, 0, 0, 0};

    short8 BA[4], BB[4];
    #pragma unroll
    for (int nb = 0; nb < 4; ++nb) BA[nb] = *(const short8*)(wp + (size_t)nb * 512);

    #pragma unroll 1
    for (int t = 0; t < NT; ++t) {
      #pragma unroll
      for (int s = 0; s < 4; ++s) {
        const int g = t * 4 + s;
        const int gn = (g + 1 < 32) ? g + 1 : 31;
        if ((s & 1) == 0) {
          #pragma unroll
          for (int nb = 0; nb < 4; ++nb)
            BB[nb] = *(const short8*)(wp + (size_t)(gn * 4 + nb) * 512);
          #pragma unroll
          for (int i = 0; i < MT; ++i) {
            short8 am = (tys[i] == t) ? A[i][s] : z8;
            #pragma unroll
            for (int nb = 0; nb < 4; ++nb)
              acc[i][nb] = __builtin_amdgcn_mfma_f32_16x16x32_bf16(am, BA[nb], acc[i][nb], 0, 0, 0);
          }
        } else {
          #pragma unroll
          for (int nb = 0; nb < 4; ++nb)
            BA[nb] = *(const short8*)(wp + (size_t)(gn * 4 + nb) * 512);
          #pragma unroll
          for (int i = 0; i < MT; ++i) {
            short8 am = (tys[i] == t) ? A[i][s] : z8;
            #pragma unroll
            for (int nb = 0; nb < 4; ++nb)
              acc[i][nb] = __builtin_amdgcn_mfma_f32_16x16x32_bf16(am, BB[nb], acc[i][nb], 0, 0, 0);
          }
        }
      }
    }

    #pragma unroll
    for (int i = 0; i < MT; ++i) {
      const int rbase = base + i * 16 + q * 4;
      if (rbase >= N) continue;
      int4 tyv;
      if (rbase + 3 < N) {
        tyv = *(const int4*)(nty + rbase);
      } else {
        tyv.x = rbase + 0 < N ? nty[rbase + 0] : 0;
        tyv.y = rbase + 1 < N ? nty[rbase + 1] : 0;
        tyv.z = rbase + 2 < N ? nty[rbase + 2] : 0;
        tyv.w = rbase + 3 < N ? nty[rbase + 3] : 0;
      }
      const int trs[4] = {tyv.x, tyv.y, tyv.z, tyv.w};
      #pragma unroll
      for (int r = 0; r < 4; ++r) {
        const int row = rbase + r;
        if (row < N) {
          const float* br = b + trs[r] * OUTF + c;
          float* orow = out + (size_t)row * OUTF + c;
          #pragma unroll
          for (int nb = 0; nb < 4; ++nb)
            orow[nb * 16] = acc[i][nb][r] + br[nb * 16];
        }
      }
    }
  }
}

extern "C" void kernel_launch(void* const* d_in, const int* in_sizes, int n_in,
                              void* d_out, int out_size, void* d_ws, size_t ws_size,
                              hipStream_t stream) {
  const float* x  = (const float*)d_in[0];
  const int*   nt = (const int*)d_in[1];
  const float* W  = (const float*)d_in[2];
  const float* b  = (const float*)d_in[3];
  float* out = (float*)d_out;
  const int N = in_sizes[1];
  short* wbf = (short*)d_ws;

  // ws layout: [0,128K) wbf | ints at 128K: cnt[8], poff[9] (@+8), pad,
  //            cursor[8] (@+24), pad, idx[] (@+64, capacity N+576)
  const size_t need = 131072 + sizeof(int) * (size_t)(64 + N + 576);

  if (ws_size >= need && N > 0) {
    int* meta   = (int*)((char*)d_ws + 131072);
    int* cnt    = meta;
    int* poff   = meta + 8;
    int* cursor = meta + 24;
    int* idx    = meta + 64;

    int hb = (N + 1023) / 1024;
    if (hb > 2048) hb = 2048;

    hl_wconv<<<32, 256, 0, stream>>>(W, wbf, cnt);
    hl_hist<<<hb, 256, 0, stream>>>(nt, N, cnt);
    hl_off<<<1, 64, 0, stream>>>(cnt, poff, cursor, idx);
    hl_scat<<<hb, 256, 0, stream>>>(nt, N, cursor, idx);

    const int npass_max = (((N + 63) & ~63) + NT * 64) / 32;
    const int gb = (npass_max + 3) / 4;
    hl_bgemm<<<gb, 256, 0, stream>>>(x, wbf, b, idx, poff, out);
  } else {
    hl_wconv<<<32, 256, 0, stream>>>(W, wbf, nullptr);
    hl_main_masked<<<512, 256, 0, stream>>>(x, nt, wbf, b, out, N);
  }
}

// Round 2
// 412.814 us; speedup vs baseline: 1.0375x; 1.0232x over previous
//
#include <hip/hip_runtime.h>
#include <hip/hip_bf16.h>

#define NT   8
#define INF  128
#define OUTF 64
#define BR   128    // rows per block (local binning granularity)

typedef __attribute__((ext_vector_type(8))) short short8;   // 8 bf16 (4 VGPRs)
typedef __attribute__((ext_vector_type(4))) short short4v;  // 4 bf16 (2 VGPRs)
typedef __attribute__((ext_vector_type(4))) float f32x4;

__device__ __forceinline__ short f2bf(float f) {
  __hip_bfloat16 h = __float2bfloat16(f);
  return __builtin_bit_cast(short, h);
}

// ---------------------------------------------------------------------------
// wbf[128 * 512] shorts (128 KB) in d_ws: W as bf16 in MFMA B-fragment order.
//   frag fi = (t*4 + s)*4 + nb, lane(q,c), j:
//   wbf[fi*512 + lane*8 + j] = bf16( W[t][s*32 + q*8 + j][nb*16 + c] )
// (verified in earlier rounds)
// ---------------------------------------------------------------------------
__global__ void hl_wconv(const float* __restrict__ W, short* __restrict__ wbf) {
  const int tid   = blockIdx.x * blockDim.x + threadIdx.x;  // 0..8191
  const int combo = tid >> 6;                               // 0..127 == fi
  const int lane  = tid & 63;
  const int t = combo >> 4, s = (combo >> 2) & 3, nb = combo & 3;
  const int q = lane >> 4, c = lane & 15;
  const float* Wt = W + t * INF * OUTF;
  short8 v;
  #pragma unroll
  for (int j = 0; j < 8; ++j)
    v[j] = f2bf(Wt[(s * 32 + q * 8 + j) * OUTF + nb * 16 + c]);
  *(short8*)(wbf + (size_t)tid * 8) = v;
}

// ---------------------------------------------------------------------------
// Locally-binned GEMM. One block owns 128 consecutive rows:
//   1. stage x rows -> LDS as bf16, 16-B-chunk XOR swizzle (^((row&7)<<4))
//   2. bin rows by type in-block (LDS atomic rank -> lorder[])
//   3. one MFMA tile per (type, 16-row chunk): A gathered from LDS by lorder,
//      B streamed from L2-hot wbf (128 KB), bias + scatter-store within the
//      block's 32-KB out window.
// E[tiles] ~= 11.7 per 128 rows (vs 8 ideal) -> ~1.46x MFMA work, but MFMA is
// ~7 us chip-total; kernel is a pure stream of x (256 MB) + out (128 MB).
// Fragment mappings (verified rounds 1-2 of prior session):
//   A: m = lane&15, k = q*8 + j (per s-step of 32)
//   B: k = s*32 + q*8 + j, n = nb*16 + c
//   C/D: n = lane&15, m = q*4 + reg
// ---------------------------------------------------------------------------
__global__ __launch_bounds__(256, 4) void hl_lb(
    const float* __restrict__ x, const int* __restrict__ nty,
    const short* __restrict__ wbf, const float* __restrict__ b,
    float* __restrict__ out, int N) {
  __shared__ short xs[BR * 128];          // 32 KB swizzled bf16 tile
  __shared__ int lcnt[NT], cbase[NT];
  __shared__ int lorder[BR];
  __shared__ int descs[16];               // t | valid<<3 | loff<<8
  __shared__ int ndesc;

  const int tid   = threadIdx.x;
  const int base  = blockIdx.x * BR;
  const int nrows = min(BR, N - base);

  if (tid < NT) lcnt[tid] = 0;
  __syncthreads();

  // ---- stage: flat f32x4 sweep, fully coalesced; bf16 + chunk swizzle ----
  const int nf4 = nrows * 32;             // 32 f32x4 per row
  for (int f4 = tid; f4 < nf4; f4 += 256) {
    const int row = f4 >> 5, q4 = f4 & 31;
    f32x4 v = *(const f32x4*)(x + (size_t)(base + row) * INF + q4 * 4);
    short4v s4;
    s4[0] = f2bf(v[0]); s4[1] = f2bf(v[1]);
    s4[2] = f2bf(v[2]); s4[3] = f2bf(v[3]);
    const int byt = (q4 * 8) ^ ((row & 7) << 4);
    *(short4v*)((char*)xs + row * 256 + byt) = s4;
  }

  // ---- per-type rank (order within type irrelevant) ----
  int myrank = 0, myty = 0;
  if (tid < nrows) {
    myty = nty[base + tid];
    myrank = atomicAdd(&lcnt[myty], 1);
  }
  __syncthreads();

  if (tid == 0) {
    int o = 0, nd = 0;
    #pragma unroll
    for (int t = 0; t < NT; ++t) {
      cbase[t] = o;
      const int cn = lcnt[t];
      for (int j = 0; j < cn; j += 16) {
        const int valid = min(16, cn - j);
        descs[nd++] = t | (valid << 3) | ((o + j) << 8);
      }
      o += cn;
    }
    ndesc = nd;
  }
  __syncthreads();
  if (tid < nrows) lorder[cbase[myty] + myrank] = tid;
  __syncthreads();

  // ---- tile loop: waves round-robin over descriptors ----
  const int wave = tid >> 6, lane = tid & 63;
  const int q = lane >> 4, c = lane & 15;
  const int nd = ndesc;
  const short* wp = wbf + lane * 8;       // + fi*512 per fragment

  for (int i = wave; i < nd; i += 4) {
    const int d = descs[i];
    const int t = d & 7, valid = (d >> 3) & 31, loff = d >> 8;

    // A fragments: output row m = c, gathered from LDS by lorder
    const int am   = c < valid ? c : valid - 1;     // dup row for pad lanes
    const int lrow = lorder[loff + am];
    const char* arow = (const char*)xs + lrow * 256;
    const int sw = (lrow & 7) << 4;
    short8 A[4];
    #pragma unroll
    for (int s = 0; s < 4; ++s)
      A[s] = *(const short8*)(arow + ((s * 64 + q * 16) ^ sw));

    f32x4 acc[4];
    #pragma unroll
    for (int nb = 0; nb < 4; ++nb) acc[nb] = (f32x4){0, 0, 0, 0};

    #pragma unroll
    for (int s = 0; s < 4; ++s) {
      #pragma unroll
      for (int nb = 0; nb < 4; ++nb) {
        short8 B = *(const short8*)(wp + (size_t)(((t * 4 + s) * 4 + nb)) * 512);
        acc[nb] = __builtin_amdgcn_mfma_f32_16x16x32_bf16(A[s], B, acc[nb], 0, 0, 0);
      }
    }

    // epilogue: D row m = q*4+r, col = c + nb*16; single-type bias
    float bv[4];
    #pragma unroll
    for (int nb = 0; nb < 4; ++nb) bv[nb] = b[t * OUTF + nb * 16 + c];
    #pragma unroll
    for (int r = 0; r < 4; ++r) {
      const int m = q * 4 + r;
      if (m < valid) {
        const int grow = base + lorder[loff + m];
        float* orow = out + (size_t)grow * OUTF + c;
        #pragma unroll
        for (int nb = 0; nb < 4; ++nb)
          orow[nb * 16] = acc[nb][r] + bv[nb];
      }
    }
  }
}

extern "C" void kernel_launch(void* const* d_in, const int* in_sizes, int n_in,
                              void* d_out, int out_size, void* d_ws, size_t ws_size,
                              hipStream_t stream) {
  const float* x  = (const float*)d_in[0];
  const int*   nt = (const int*)d_in[1];
  const float* W  = (const float*)d_in[2];
  const float* b  = (const float*)d_in[3];
  float* out = (float*)d_out;
  const int N = in_sizes[1];
  short* wbf = (short*)d_ws;              // 128 KB (ws >= 128 KB, proven)

  hl_wconv<<<32, 256, 0, stream>>>(W, wbf);
  const int gb = (N + BR - 1) / BR;
  hl_lb<<<gb, 256, 0, stream>>>(x, nt, wbf, b, out, N);
}